// Round 2
// baseline (116.365 us; speedup 1.0000x reference)
//
#include <hip/hip_runtime.h>

constexpr int Bn = 8192;   // batch
constexpr int Dn = 512;    // feature dim
#define EPSF 1e-7f
#define MARGINF 1.0f

__device__ __forceinline__ void amax_combine(float& bv, int& bi, float v, int i) {
    // argmax with first-index tie-break (matches jnp.argmax)
    if (v > bv || (v == bv && i < bi)) { bv = v; bi = i; }
}

// Detect whether labels buffer is actually int64 (odd int32 words all zero)
__global__ void detect_labels_kernel(const int* __restrict__ labels, int* __restrict__ flag) {
    int any = 0;
    for (int k = 1; k < 128; k += 2) any |= labels[k];
    *flag = (any == 0) ? 1 : 0;
}

__global__ __launch_bounds__(256) void triplet_main(
    const float* __restrict__ feats,
    const int*   __restrict__ labels,
    const float* __restrict__ noise,
    const int*   __restrict__ flag64,
    float*       __restrict__ losses)
{
    __shared__ unsigned slab_u[Bn / 4];   // 8 KB: labels as bytes
    char* slab = (char*)slab_u;
    __shared__ float swv[8];
    __shared__ int   swi[8];
    __shared__ float sdist[8];
    __shared__ int   sidx[2];

    const int row  = blockIdx.x;
    const int tid  = threadIdx.x;
    const int lane = tid & 63;
    const int wv   = tid >> 6;

    // ---- stage labels into LDS as bytes ----
    if (*flag64) {
        const long long* l8 = (const long long*)labels;
        for (int k = tid; k < Bn; k += 256) slab[k] = (char)l8[k];
    } else {
        for (int k = tid; k < Bn / 4; k += 256) {
            int4 v = ((const int4*)labels)[k];
            slab[k * 4 + 0] = (char)v.x;
            slab[k * 4 + 1] = (char)v.y;
            slab[k * 4 + 2] = (char)v.z;
            slab[k * 4 + 3] = (char)v.w;
        }
    }
    __syncthreads();

    const char myLab = slab[row];

    // ---- masked argmax over noise[0][row][:] (pos) and noise[1][row][:] (neg) ----
    float pbv = -1.0f, nbv = -1.0f;
    int   pbi = 0x7FFFFFFF, nbi = 0x7FFFFFFF;

    const float* __restrict__ n0 = noise + (size_t)row * Bn;
    const float* __restrict__ n1 = noise + (size_t)Bn * Bn + (size_t)row * Bn;

    for (int j = tid * 4; j < Bn; j += 256 * 4) {
        float4 v0 = *(const float4*)(n0 + j);
        float4 v1 = *(const float4*)(n1 + j);
        unsigned lw = slab_u[j >> 2];
        char l0 = (char)(lw & 255u);
        char l1 = (char)((lw >> 8) & 255u);
        char l2 = (char)((lw >> 16) & 255u);
        char l3 = (char)((lw >> 24) & 255u);
        amax_combine(pbv, pbi, (l0 == myLab) ? v0.x : -1.0f, j + 0);
        amax_combine(pbv, pbi, (l1 == myLab) ? v0.y : -1.0f, j + 1);
        amax_combine(pbv, pbi, (l2 == myLab) ? v0.z : -1.0f, j + 2);
        amax_combine(pbv, pbi, (l3 == myLab) ? v0.w : -1.0f, j + 3);
        amax_combine(nbv, nbi, (l0 != myLab) ? v1.x : -1.0f, j + 0);
        amax_combine(nbv, nbi, (l1 != myLab) ? v1.y : -1.0f, j + 1);
        amax_combine(nbv, nbi, (l2 != myLab) ? v1.z : -1.0f, j + 2);
        amax_combine(nbv, nbi, (l3 != myLab) ? v1.w : -1.0f, j + 3);
    }

    // wave-level argmax reduce
    for (int off = 32; off; off >>= 1) {
        float ov = __shfl_down(pbv, off, 64);
        int   oi = __shfl_down(pbi, off, 64);
        amax_combine(pbv, pbi, ov, oi);
        ov = __shfl_down(nbv, off, 64);
        oi = __shfl_down(nbi, off, 64);
        amax_combine(nbv, nbi, ov, oi);
    }
    if (lane == 0) { swv[wv] = pbv; swi[wv] = pbi; swv[wv + 4] = nbv; swi[wv + 4] = nbi; }
    __syncthreads();

    if (tid == 0) {
        float bv = swv[0]; int bi = swi[0];
        for (int k = 1; k < 4; ++k) amax_combine(bv, bi, swv[k], swi[k]);
        float bv2 = swv[4]; int bi2 = swi[4];
        for (int k = 5; k < 8; ++k) amax_combine(bv2, bi2, swv[k], swi[k]);
        sidx[0] = bi;
        sidx[1] = (bv2 >= 0.0f) ? bi2 : row;   // has_neg fallback -> anchor
    }
    __syncthreads();

    const int pi = sidx[0];
    const int ni = sidx[1];

    // ---- triplet distances: each thread handles 2 contiguous floats ----
    const float2 a  = ((const float2*)(feats + (size_t)row * Dn))[tid];
    const float2 p  = ((const float2*)(feats + (size_t)pi  * Dn))[tid];
    const float2 nn = ((const float2*)(feats + (size_t)ni  * Dn))[tid];

    float dx = a.x - p.x + EPSF, dy = a.y - p.y + EPSF;
    float dap = dx * dx + dy * dy;
    dx = a.x - nn.x + EPSF; dy = a.y - nn.y + EPSF;
    float dan = dx * dx + dy * dy;

    for (int off = 32; off; off >>= 1) {
        dap += __shfl_down(dap, off, 64);
        dan += __shfl_down(dan, off, 64);
    }
    if (lane == 0) { sdist[wv] = dap; sdist[wv + 4] = dan; }
    __syncthreads();

    if (tid == 0) {
        float sap = sdist[0] + sdist[1] + sdist[2] + sdist[3];
        float san = sdist[4] + sdist[5] + sdist[6] + sdist[7];
        losses[row] = fmaxf(sqrtf(sap) - sqrtf(san) + MARGINF, 0.0f);
    }
}

// deterministic mean over Bn losses, single block
__global__ __launch_bounds__(256) void reduce_mean_kernel(
    const float* __restrict__ losses, float* __restrict__ out)
{
    const int tid  = threadIdx.x;
    const int lane = tid & 63;
    const int wv   = tid >> 6;
    float s = 0.0f;
    for (int k = tid; k < Bn; k += 256) s += losses[k];
    for (int off = 32; off; off >>= 1) s += __shfl_down(s, off, 64);
    __shared__ float sw[4];
    if (lane == 0) sw[wv] = s;
    __syncthreads();
    if (tid == 0) out[0] = (sw[0] + sw[1] + sw[2] + sw[3]) * (1.0f / (float)Bn);
}

extern "C" void kernel_launch(void* const* d_in, const int* in_sizes, int n_in,
                              void* d_out, int out_size, void* d_ws, size_t ws_size,
                              hipStream_t stream) {
    const float* feats  = (const float*)d_in[0];
    const int*   labels = (const int*)d_in[1];
    const float* noise  = (const float*)d_in[2];
    float* out = (float*)d_out;

    float* losses = (float*)d_ws;          // Bn floats
    int*   flag   = (int*)d_ws + Bn;       // 1 int

    detect_labels_kernel<<<1, 1, 0, stream>>>(labels, flag);
    triplet_main<<<Bn, 256, 0, stream>>>(feats, labels, noise, flag, losses);
    reduce_mean_kernel<<<1, 256, 0, stream>>>(losses, out);
}

// Round 3
// 113.208 us; speedup vs baseline: 1.0279x; 1.0279x over previous
//
#include <hip/hip_runtime.h>

constexpr int Bn = 8192;   // batch
constexpr int Dn = 512;    // feature dim
#define EPSF 1e-7f
#define MARGINF 1.0f

__device__ __forceinline__ void amax_combine(float& bv, int& bi, float v, int i) {
    // argmax with first-index tie-break (matches jnp.argmax)
    if (v > bv || (v == bv && i < bi)) { bv = v; bi = i; }
}

// Pack labels (int64 or int32, values 0/1) into a byte array, 4 per u32 word.
// Also performs the dtype detection (odd int32 words all zero => int64).
__global__ __launch_bounds__(256) void pack_labels_kernel(const int* __restrict__ labels,
                                                          unsigned* __restrict__ packed) {
    __shared__ int s_any;
    const int tid = threadIdx.x;
    if (tid == 0) s_any = 0;
    __syncthreads();
    if (tid < 128 && labels[2 * tid + 1] != 0) atomicOr(&s_any, 1);
    __syncthreads();
    const bool is64 = (s_any == 0);

    if (is64) {
        const long long* l8 = (const long long*)labels;
        for (int w = tid; w < Bn / 4; w += 256) {
            unsigned b0 = (unsigned)l8[w * 4 + 0] & 0xffu;
            unsigned b1 = (unsigned)l8[w * 4 + 1] & 0xffu;
            unsigned b2 = (unsigned)l8[w * 4 + 2] & 0xffu;
            unsigned b3 = (unsigned)l8[w * 4 + 3] & 0xffu;
            packed[w] = b0 | (b1 << 8) | (b2 << 16) | (b3 << 24);
        }
    } else {
        for (int w = tid; w < Bn / 4; w += 256) {
            int4 v = ((const int4*)labels)[w];
            packed[w] = ((unsigned)v.x & 0xffu) | (((unsigned)v.y & 0xffu) << 8) |
                        (((unsigned)v.z & 0xffu) << 16) | (((unsigned)v.w & 0xffu) << 24);
        }
    }
}

__global__ __launch_bounds__(256) void triplet_main(
    const float*    __restrict__ feats,
    const unsigned* __restrict__ packed,   // Bn/4 words of packed label bytes
    const float*    __restrict__ noise,
    float*          __restrict__ losses)
{
    __shared__ unsigned slab_u[Bn / 4];   // 8 KB packed label bytes
    __shared__ float swv[8];
    __shared__ int   swi[8];
    __shared__ float sdist[8];
    __shared__ int   sidx[2];

    const int row  = blockIdx.x;
    const int tid  = threadIdx.x;
    const int lane = tid & 63;
    const int wv   = tid >> 6;

    // ---- stage packed labels into LDS (8 KB, L1-resident across blocks) ----
    for (int k = tid; k < Bn / 16; k += 256)
        ((uint4*)slab_u)[k] = ((const uint4*)packed)[k];
    __syncthreads();

    const unsigned myLab = (slab_u[row >> 2] >> ((row & 3) * 8)) & 0xffu;

    // ---- masked argmax over noise[0][row][:] (pos) and noise[1][row][:] (neg) ----
    // 4 independent slot-accumulators break the dependent compare chain.
    float pbv[4] = {-1.0f, -1.0f, -1.0f, -1.0f};
    float nbv[4] = {-1.0f, -1.0f, -1.0f, -1.0f};
    int   pbi[4] = {0x7FFFFFFF, 0x7FFFFFFF, 0x7FFFFFFF, 0x7FFFFFFF};
    int   nbi[4] = {0x7FFFFFFF, 0x7FFFFFFF, 0x7FFFFFFF, 0x7FFFFFFF};

    const float* __restrict__ n0 = noise + (size_t)row * Bn;
    const float* __restrict__ n1 = noise + (size_t)Bn * Bn + (size_t)row * Bn;

    for (int j = tid * 4; j < Bn; j += 256 * 4) {
        float4 v0 = *(const float4*)(n0 + j);
        float4 v1 = *(const float4*)(n1 + j);
        unsigned lw = slab_u[j >> 2];
        const float* f0 = (const float*)&v0;
        const float* f1 = (const float*)&v1;
#pragma unroll
        for (int k = 0; k < 4; ++k) {
            unsigned lk = (lw >> (k * 8)) & 0xffu;
            // within a slot, indices strictly increase -> strictly-greater keeps first max
            float cp = (lk == myLab) ? f0[k] : -1.0f;
            if (cp > pbv[k]) { pbv[k] = cp; pbi[k] = j + k; }
            float cn = (lk != myLab) ? f1[k] : -1.0f;
            if (cn > nbv[k]) { nbv[k] = cn; nbi[k] = j + k; }
        }
    }

    // merge slots (tie-break on index: lower slot = lower index for same j)
    float pv = pbv[0]; int pi_ = pbi[0];
    float nv = nbv[0]; int ni_ = nbi[0];
#pragma unroll
    for (int k = 1; k < 4; ++k) {
        amax_combine(pv, pi_, pbv[k], pbi[k]);
        amax_combine(nv, ni_, nbv[k], nbi[k]);
    }

    // wave-level argmax reduce
    for (int off = 32; off; off >>= 1) {
        float ov = __shfl_down(pv, off, 64);
        int   oi = __shfl_down(pi_, off, 64);
        amax_combine(pv, pi_, ov, oi);
        ov = __shfl_down(nv, off, 64);
        oi = __shfl_down(ni_, off, 64);
        amax_combine(nv, ni_, ov, oi);
    }
    if (lane == 0) { swv[wv] = pv; swi[wv] = pi_; swv[wv + 4] = nv; swi[wv + 4] = ni_; }
    __syncthreads();

    if (tid == 0) {
        float bv = swv[0]; int bi = swi[0];
        for (int k = 1; k < 4; ++k) amax_combine(bv, bi, swv[k], swi[k]);
        float bv2 = swv[4]; int bi2 = swi[4];
        for (int k = 5; k < 8; ++k) amax_combine(bv2, bi2, swv[k], swi[k]);
        sidx[0] = bi;
        sidx[1] = (bv2 >= 0.0f) ? bi2 : row;   // has_neg fallback -> anchor
    }
    __syncthreads();

    const int pi = sidx[0];
    const int ni = sidx[1];

    // ---- triplet distances: each thread handles 2 contiguous floats ----
    const float2 a  = ((const float2*)(feats + (size_t)row * Dn))[tid];
    const float2 p  = ((const float2*)(feats + (size_t)pi  * Dn))[tid];
    const float2 nn = ((const float2*)(feats + (size_t)ni  * Dn))[tid];

    float dx = a.x - p.x + EPSF, dy = a.y - p.y + EPSF;
    float dap = dx * dx + dy * dy;
    dx = a.x - nn.x + EPSF; dy = a.y - nn.y + EPSF;
    float dan = dx * dx + dy * dy;

    for (int off = 32; off; off >>= 1) {
        dap += __shfl_down(dap, off, 64);
        dan += __shfl_down(dan, off, 64);
    }
    if (lane == 0) { sdist[wv] = dap; sdist[wv + 4] = dan; }
    __syncthreads();

    if (tid == 0) {
        float sap = sdist[0] + sdist[1] + sdist[2] + sdist[3];
        float san = sdist[4] + sdist[5] + sdist[6] + sdist[7];
        losses[row] = fmaxf(sqrtf(sap) - sqrtf(san) + MARGINF, 0.0f);
    }
}

// deterministic mean over Bn losses, single block
__global__ __launch_bounds__(256) void reduce_mean_kernel(
    const float* __restrict__ losses, float* __restrict__ out)
{
    const int tid  = threadIdx.x;
    const int lane = tid & 63;
    const int wv   = tid >> 6;
    float s = 0.0f;
    for (int k = tid; k < Bn; k += 256) s += losses[k];
    for (int off = 32; off; off >>= 1) s += __shfl_down(s, off, 64);
    __shared__ float sw[4];
    if (lane == 0) sw[wv] = s;
    __syncthreads();
    if (tid == 0) out[0] = (sw[0] + sw[1] + sw[2] + sw[3]) * (1.0f / (float)Bn);
}

extern "C" void kernel_launch(void* const* d_in, const int* in_sizes, int n_in,
                              void* d_out, int out_size, void* d_ws, size_t ws_size,
                              hipStream_t stream) {
    const float* feats  = (const float*)d_in[0];
    const int*   labels = (const int*)d_in[1];
    const float* noise  = (const float*)d_in[2];
    float* out = (float*)d_out;

    float*    losses = (float*)d_ws;                       // Bn floats (32 KB)
    unsigned* packed = (unsigned*)((char*)d_ws + 32768);   // Bn/4 words (8 KB)

    pack_labels_kernel<<<1, 256, 0, stream>>>(labels, packed);
    triplet_main<<<Bn, 256, 0, stream>>>(feats, packed, noise, losses);
    reduce_mean_kernel<<<1, 256, 0, stream>>>(losses, out);
}